// Round 1
// baseline (2240.938 us; speedup 1.0000x reference)
//
#include <hip/hip_runtime.h>
#include <hip/hip_bf16.h>

#define N_NODES 100000
#define N_EDGES 1600000
#define F_IN 128
#define HID 64
#define N_GRAPHS 1024

// fine dst-partition: bucket = dst>>9 (512 nodes/bucket)
#define SH 9
#define NBU 196        // buckets used: ceil(100000/512)
#define NB 200         // allocated
#define BCAP 9728      // mean 8192 + 17 sigma
#define EPB 8192       // edges per k_part block (196 blocks exactly)
#define NSLICE 4       // 4 feature slices x 16 feats; slice table = 3.2 MB (fits XCD L2)

typedef __attribute__((ext_vector_type(8))) short bf16x8;
typedef __attribute__((ext_vector_type(4))) float f32x4;
typedef __attribute__((ext_vector_type(4))) unsigned int u32x4;

// ---------------- bf16 bit helpers --------------------------------------------
__device__ __forceinline__ unsigned short f2bf(float f) {
    __hip_bfloat16 h = __float2bfloat16(f);   // RNE
    return *reinterpret_cast<unsigned short*>(&h);
}
__device__ __forceinline__ float bf2f(unsigned int u) {
    return __uint_as_float(u << 16);
}

// ---------------- dual-path load helpers (wire dtype resolved at runtime) -----
__device__ __forceinline__ float loadf(const void* p, size_t i, int f32) {
    if (f32) return ((const float*)p)[i];
    return __bfloat162float(((const __hip_bfloat16*)p)[i]);
}
__device__ __forceinline__ int loadi(const void* p, size_t i, int i64) {
    if (i64) return (int)((const long long*)p)[i];
    return ((const int*)p)[i];
}

// ---------------- init: wire detect + zero small counters ---------------------
__global__ void k_init(const unsigned int* __restrict__ xw_,
                       const unsigned int* __restrict__ ei_,
                       int* __restrict__ flags,
                       int* __restrict__ gcnt, int* __restrict__ bcnt) {
    __shared__ int cnt_f, cnt_i;
    int t = threadIdx.x;
    if (t == 0) { cnt_f = 0; cnt_i = 0; }
    __syncthreads();
    unsigned int w = xw_[t];
    unsigned int e = (w >> 7) & 0xFFu;
    if (e >= 100u && e <= 140u) atomicAdd(&cnt_f, 1);
    unsigned int iw = ei_[2 * t + 1];
    if (iw == 0u) atomicAdd(&cnt_i, 1);
    for (int i = t; i < N_GRAPHS; i += 256) gcnt[i] = 0;
    for (int i = t; i < NB; i += 256) bcnt[i] = 0;
    __syncthreads();
    if (t == 0) {
        flags[0] = (cnt_f < 180) ? 1 : 0;   // 1 => fp32 wire
        flags[1] = (cnt_i >= 128) ? 1 : 0;  // 1 => int64 wire
    }
}

// ---------------- phase A: partition by dst>>9, two-pass fat blocks -----------
// 196 blocks x 8192 edges. Pass 1: LDS bucket counts -> ONE global reserve per
// bucket per block. Pass 2: re-read edges (L3-hot), re-rank via zeroed LDS hist,
// write packed (src<<9 | dst&511). Batch counts pre-aggregated in LDS hist.
__global__ __launch_bounds__(256) void k_part(const void* __restrict__ ei,
                                              const void* __restrict__ batch,
                                              int* __restrict__ bcnt,
                                              int* __restrict__ gcnt,
                                              unsigned int* __restrict__ packed,
                                              const int* __restrict__ flags) {
    int I64 = flags[1];
    __shared__ int hist[NB];
    __shared__ int base[NB];
    __shared__ int ghist[N_GRAPHS];   // 4 KB
    int t = threadIdx.x;
    if (t < NB) hist[t] = 0;
    for (int i = t; i < N_GRAPHS; i += 256) ghist[i] = 0;
    __syncthreads();
    // batch counting: block covers nodes [blk*512, blk*512+512)
    for (int it = 0; it < 2; ++it) {
        int n = blockIdx.x * 512 + it * 256 + t;
        if (n < N_NODES) atomicAdd(&ghist[loadi(batch, n, I64)], 1);
    }
    // edge pass 1: bucket counts
    int e0 = blockIdx.x * EPB;
#pragma unroll 4
    for (int it = 0; it < EPB / 256; ++it) {
        int e = e0 + it * 256 + t;
        if (e < N_EDGES) {
            int d = loadi(ei, (size_t)N_EDGES + e, I64);
            atomicAdd(&hist[d >> SH], 1);
        }
    }
    __syncthreads();
    if (t < NB) {
        base[t] = hist[t] ? atomicAdd(&bcnt[t], hist[t]) : 0;
        hist[t] = 0;   // reuse as pass-2 rank counter
    }
    for (int i = t; i < N_GRAPHS; i += 256)
        if (ghist[i]) atomicAdd(&gcnt[i], ghist[i]);
    __syncthreads();
    // edge pass 2: rank + write
#pragma unroll 4
    for (int it = 0; it < EPB / 256; ++it) {
        int e = e0 + it * 256 + t;
        if (e < N_EDGES) {
            int s = loadi(ei, e, I64);
            int d = loadi(ei, (size_t)N_EDGES + e, I64);
            int b = d >> SH;
            int r = atomicAdd(&hist[b], 1);
            int pos = base[b] + r;
            if (pos < BCAP)
                packed[(size_t)b * BCAP + pos] = ((unsigned int)s << SH) | (unsigned int)(d & 511);
        }
    }
}

// ---------------- hist: in-degree -> dis only (CSR no longer needed) ----------
__global__ __launch_bounds__(256) void k_hist(const unsigned int* __restrict__ packed,
                                              const int* __restrict__ bcnt,
                                              float* __restrict__ dis) {
    __shared__ int hist[512];
    int b = blockIdx.x;
    int t = threadIdx.x;
    int n = bcnt[b];
    if (n > BCAP) n = BCAP;
    for (int i = t; i < 512; i += 256) hist[i] = 0;
    __syncthreads();
    const unsigned int* pb = packed + (size_t)b * BCAP;
    for (int i = t; i < n; i += 256)
        atomicAdd(&hist[pb[i] & 511u], 1);
    __syncthreads();
    int nbase = b << SH;
    for (int i = t; i < 512; i += 256) {
        int node = nbase + i;
        if (node < N_NODES)
            dis[node] = rsqrtf((float)hist[i] + 1.0f);
    }
}

// ---------------- graph scan: gcnt (1024) -> gptr, one block ------------------
__global__ void k_gscan(const int* __restrict__ gcnt, int* __restrict__ gptr) {
    __shared__ int s[512];
    int t = threadIdx.x;
    int a = gcnt[2 * t], bq = gcnt[2 * t + 1];
    int ps = a + bq;
    s[t] = ps;
    __syncthreads();
    for (int off = 1; off < 512; off <<= 1) {
        int x = (t >= off) ? s[t - off] : 0;
        __syncthreads();
        s[t] += x;
        __syncthreads();
    }
    int excl = s[t] - ps;
    gptr[2 * t] = excl;
    gptr[2 * t + 1] = excl + a;
    if (t == 511) gptr[1024] = s[511];
}

// ---------------- MFMA GEMM: in[N,K] @ W[K,64] -> out slice-major bf16 --------
// out layout: [4 slices][N_NODES][16 feats] bf16 ("slice-major"): slice s is a
// contiguous 3.2 MB block -> fits a single XCD L2 during aggregation.
// in_sm: input is slice-major (layers 2/3, K=64 only); else node-major wire.
template <int K>
__global__ __launch_bounds__(256) void k_gemm(const void* __restrict__ x,
                                              const void* __restrict__ W,
                                              const float* __restrict__ dis,
                                              unsigned short* __restrict__ out,  // bf16 bits
                                              const int* __restrict__ flags,
                                              int x_is_f32, int in_sm) {
    int Wf32 = flags[0];
    int xF32 = (x_is_f32 < 0) ? Wf32 : x_is_f32;
    __shared__ unsigned short Wt[64][K + 8];
    __shared__ unsigned short xs[32][K + 8];
    int t = threadIdx.x;
    int wave = t >> 6, lane = t & 63;
    int quad = lane >> 4, l16 = lane & 15;

    for (int id = t; id < 64 * K; id += 256) {
        int k = id >> 6, n = id & 63;
        Wt[n][k] = f2bf(loadf(W, id, Wf32));
    }
    __syncthreads();

    bf16x8 bfrag[K / 32];
#pragma unroll
    for (int c = 0; c < K / 32; ++c)
        bfrag[c] = *reinterpret_cast<bf16x8*>(&Wt[wave * 16 + l16][c * 32 + quad * 8]);

    const int ngroups = (N_NODES + 31) / 32;
    for (int g = blockIdx.x; g < ngroups; g += gridDim.x) {
        __syncthreads();
        int row0 = g * 32;
        if (in_sm) {
            // slice-major input (K==64): 64 consecutive threads read 1 KB
            // contiguous per slice (rows are 32 B apart within a slice).
            for (int cid = t; cid < 4 * K; cid += 256) {
                int slice = cid >> 6, i = cid & 63;
                int rr = i >> 1, half = i & 1;
                int r = row0 + rr;
                u32x4 val = {0u, 0u, 0u, 0u};
                if (r < N_NODES)
                    val = ((const u32x4*)x)[((size_t)slice * N_NODES + row0) * 2 + i];
                *reinterpret_cast<u32x4*>(&xs[rr][slice * 16 + half * 8]) = val;
            }
        } else {
            for (int cid = t; cid < 4 * K; cid += 256) {
                int rr = cid / (K / 8), c8 = cid % (K / 8);
                int r = row0 + rr;
                u32x4 val = {0u, 0u, 0u, 0u};
                if (r < N_NODES) {
                    size_t base = (size_t)r * K + c8 * 8;
                    if (xF32) {
                        const u32x4* xp = (const u32x4*)x;
                        u32x4 q0 = xp[base / 4];
                        u32x4 q1 = xp[base / 4 + 1];
                        val.x = f2bf(__uint_as_float(q0.x)) | ((unsigned int)f2bf(__uint_as_float(q0.y)) << 16);
                        val.y = f2bf(__uint_as_float(q0.z)) | ((unsigned int)f2bf(__uint_as_float(q0.w)) << 16);
                        val.z = f2bf(__uint_as_float(q1.x)) | ((unsigned int)f2bf(__uint_as_float(q1.y)) << 16);
                        val.w = f2bf(__uint_as_float(q1.z)) | ((unsigned int)f2bf(__uint_as_float(q1.w)) << 16);
                    } else {
                        val = ((const u32x4*)x)[base / 8];
                    }
                }
                *reinterpret_cast<u32x4*>(&xs[rr][c8 * 8]) = val;
            }
        }
        __syncthreads();

        f32x4 acc0 = {0.f, 0.f, 0.f, 0.f};
        f32x4 acc1 = {0.f, 0.f, 0.f, 0.f};
#pragma unroll
        for (int c = 0; c < K / 32; ++c) {
            bf16x8 a0 = *reinterpret_cast<bf16x8*>(&xs[l16][c * 32 + quad * 8]);
            bf16x8 a1 = *reinterpret_cast<bf16x8*>(&xs[16 + l16][c * 32 + quad * 8]);
            acc0 = __builtin_amdgcn_mfma_f32_16x16x32_bf16(a0, bfrag[c], acc0, 0, 0, 0);
            acc1 = __builtin_amdgcn_mfma_f32_16x16x32_bf16(a1, bfrag[c], acc1, 0, 0, 0);
        }
        // col = wave*16 + l16 -> slice = wave, within-slice feat = l16
        unsigned short* ow = out + (size_t)wave * (N_NODES * 16);
#pragma unroll
        for (int reg = 0; reg < 4; ++reg) {
            int r0 = row0 + quad * 4 + reg;
            if (r0 < N_NODES) ow[(size_t)r0 * 16 + l16] = f2bf(acc0[reg] * dis[r0]);
            int r1 = row0 + 16 + quad * 4 + reg;
            if (r1 < N_NODES) ow[(size_t)r1 * 16 + l16] = f2bf(acc1[reg] * dis[r1]);
        }
    }
}

// ---------------- edge-parallel bucketed aggregation (replaces CSR gather) ----
// grid = 98*8 = 784 blocks. XCD-affine: xcd = blk&7, slice = xcd>>1 -> each XCD
// touches ONE 3.2 MB slice (L2-resident after warm). bucket = (blk>>3)*2+(xcd&1)
// covers each (bucket, slice) pair exactly once (196 x 4).
// Per block: zero LDS acc[512][17] f32 (34.8 KB, x17 pad -> ~2-way banks),
// stream the bucket's packed edges with 4 independent 32-B row reads in flight
// per wave (latency cover), ds_add_f32 accumulate, then fused
// self-loop + bias + relu epilogue, slice-major bf16 out.
__global__ __launch_bounds__(256) void k_agg(const unsigned int* __restrict__ packed,
                                             const int* __restrict__ bcnt,
                                             const float* __restrict__ dis,
                                             const unsigned short* __restrict__ xws,
                                             const void* __restrict__ bias,
                                             unsigned short* __restrict__ out,
                                             int do_relu,
                                             const int* __restrict__ flags) {
    int F32 = flags[0];
    __shared__ float acc[512 * 17];
    int blk = blockIdx.x;
    int xcd = blk & 7;
    int s = xcd >> 1;                              // slice 0..3
    int bkt = ((blk >> 3) << 1) | (xcd & 1);       // 0..195
    int t = threadIdx.x;
    for (int i = t; i < 512 * 17; i += 256) acc[i] = 0.f;
    __syncthreads();

    int n = bcnt[bkt];
    if (n > BCAP) n = BCAP;
    const unsigned int* pb = packed + (size_t)bkt * BCAP;
    const unsigned int* xs = (const unsigned int*)(xws + (size_t)s * N_NODES * 16); // u32 = 2 feats
    int lane = t & 63, wave = t >> 6;
    int eg = lane >> 3;       // edge-in-group 0..7
    int k = lane & 7;         // feature-pair 0..7

    for (int i0 = wave * 32; i0 < n; i0 += 128) {  // 4 waves x 4 x 8 edges
        unsigned int p[4], v[4];
        int ok[4];
#pragma unroll
        for (int u = 0; u < 4; ++u) {
            int e = i0 + u * 8 + eg;
            ok[u] = (e < n);
            p[u] = ok[u] ? pb[e] : 0u;
        }
#pragma unroll
        for (int u = 0; u < 4; ++u)
            v[u] = ok[u] ? xs[(size_t)(p[u] >> SH) * 8 + k] : 0u;
#pragma unroll
        for (int u = 0; u < 4; ++u) {
            if (ok[u]) {
                int d9 = (int)(p[u] & 511u);
                unsafeAtomicAdd(&acc[d9 * 17 + 2 * k],     bf2f(v[u] & 0xFFFFu));
                unsafeAtomicAdd(&acc[d9 * 17 + 2 * k + 1], bf2f(v[u] >> 16));
            }
        }
    }
    __syncthreads();

    int nbase = bkt << SH;
    for (int idx = t; idx < 512 * 8; idx += 256) {
        int n9 = idx >> 3, kk = idx & 7;
        int node = nbase + n9;
        if (node >= N_NODES) continue;
        unsigned int sv = xs[(size_t)node * 8 + kk];      // self row (L2-hot)
        float d = dis[node];
        float b0 = loadf(bias, s * 16 + 2 * kk, F32);
        float b1 = loadf(bias, s * 16 + 2 * kk + 1, F32);
        float v0 = fmaf(acc[n9 * 17 + 2 * kk]     + bf2f(sv & 0xFFFFu), d, b0);
        float v1 = fmaf(acc[n9 * 17 + 2 * kk + 1] + bf2f(sv >> 16),     d, b1);
        if (do_relu) { v0 = fmaxf(v0, 0.f); v1 = fmaxf(v1, 0.f); }
        ((unsigned int*)out)[(size_t)s * N_NODES * 8 + (size_t)node * 8 + kk] =
            (unsigned int)f2bf(v0) | ((unsigned int)f2bf(v1) << 16);
    }
}

// ---------------- fused mean-pool + linear head (4 graphs/block) --------------
__global__ __launch_bounds__(256) void k_pool_final(const int* __restrict__ gptr,
                             const unsigned short* __restrict__ h,   // slice-major
                             const void* __restrict__ Wl, const void* __restrict__ bl,
                             void* __restrict__ out, const int* __restrict__ flags) {
    int F32 = flags[0];
    int g = blockIdx.x * 4 + (threadIdx.x >> 6);
    int lane = threadIdx.x & 63;
    if (g >= N_GRAPHS) return;
    int s = gptr[g], e = gptr[g + 1];
    size_t hbase = (size_t)(lane >> 4) * N_NODES * 16 + (lane & 15);
    float acc = 0.0f;
    for (int n = s; n < e; ++n) acc += bf2f(h[hbase + (size_t)n * 16]);
    float cnt = fmaxf((float)(e - s), 1.0f);
    float v = (acc / cnt) * loadf(Wl, lane, F32);
#pragma unroll
    for (int o = 32; o > 0; o >>= 1) v += __shfl_down(v, o, 64);
    if (lane == 0) {
        float r = v + loadf(bl, 0, F32);
        if (F32) ((float*)out)[g] = r;
        else     ((__hip_bfloat16*)out)[g] = __float2bfloat16(r);
    }
}

extern "C" void kernel_launch(void* const* d_in, const int* in_sizes, int n_in,
                              void* d_out, int out_size, void* d_ws, size_t ws_size,
                              hipStream_t stream) {
    const void* x     = d_in[0];
    const void* ei    = d_in[1];
    const void* batch = d_in[2];
    const void* W1 = d_in[3];
    const void* b1 = d_in[4];
    const void* W2 = d_in[5];
    const void* b2 = d_in[6];
    const void* W3 = d_in[7];
    const void* b3 = d_in[8];
    const void* Wl = d_in[9];
    const void* bl = d_in[10];

    // workspace layout (~34 MB)
    float* dis   = (float*)d_ws;             // 100352
    int*   gcnt  = (int*)(dis + 100352);     // 1024
    int*   gptr  = gcnt + 1024;              // 1056 (needs 1025)
    int*   bcnt  = gptr + 1056;              // 256
    int*   flags = bcnt + 256;               // 16
    unsigned int* packed = (unsigned int*)(flags + 16);    // NB*BCAP (7.8 MB)
    unsigned short* bufA = (unsigned short*)(packed + (size_t)NB * BCAP);  // bf16 slice-major (12.8 MB)
    unsigned short* bufB = bufA + (size_t)NSLICE * N_NODES * 16;           // bf16 slice-major (12.8 MB)

    const int TB = 256;
    dim3 blk(TB);

    // init: detect + zero small counters
    k_init<<<1, blk, 0, stream>>>((const unsigned int*)x, (const unsigned int*)ei,
                                  flags, gcnt, bcnt);
    // phase A partition (two-pass fat blocks, + batch counts)
    k_part<<<(N_EDGES + EPB - 1) / EPB, blk, 0, stream>>>(ei, batch, bcnt, gcnt, packed, flags);
    // in-degree -> dis
    k_hist<<<NBU, blk, 0, stream>>>(packed, bcnt, dis);
    // graph scan -> gptr
    k_gscan<<<1, 512, 0, stream>>>(gcnt, gptr);

    // ---- layer 1 ----
    k_gemm<F_IN><<<1024, blk, 0, stream>>>(x, W1, dis, bufA, flags, -1, 0);
    k_agg<<<98 * 8, blk, 0, stream>>>(packed, bcnt, dis, bufA, b1, bufB, 1, flags);
    // ---- layer 2 ----
    k_gemm<HID><<<1024, blk, 0, stream>>>(bufB, W2, dis, bufA, flags, 0, 1);
    k_agg<<<98 * 8, blk, 0, stream>>>(packed, bcnt, dis, bufA, b2, bufB, 1, flags);
    // ---- layer 3 ----
    k_gemm<HID><<<1024, blk, 0, stream>>>(bufB, W3, dis, bufA, flags, 0, 1);
    k_agg<<<98 * 8, blk, 0, stream>>>(packed, bcnt, dis, bufA, b3, bufB, 0, flags);

    // ---- pool + head ----
    k_pool_final<<<N_GRAPHS / 4, blk, 0, stream>>>(gptr, bufB, Wl, bl, d_out, flags);
}